// Round 4
// baseline (76.291 us; speedup 1.0000x reference)
//
#include <hip/hip_runtime.h>
#include <math.h>

// Problem constants
constexpr int EPG  = 512;     // edges per graph
constexpr int ETOT = 131072;  // total edges

// ws float-region offsets (floats)
constexpr size_t TAB_Q  = 0;
constexpr size_t TAB_K  = 1024;
constexpr size_t TAB_V  = 2048;
constexpr size_t TAB_S  = 3072;   // 4*64
constexpr size_t TAB_LG = 3328;   // 64
constexpr size_t OFF_H2 = 65536;  // h2 f32 [16384][64], after the shorts region
// ws short-region offsets (shorts), region starts at (short*)(ws + 4096)
constexpr int PK_Q_HI   = 0;
constexpr int PK_Q_LO   = 16384;
constexpr int PK_K_HI   = 32768;
constexpr int PK_K_LO   = 49152;
constexpr int PK_V_HI   = 65536;
constexpr int PK_V_LO   = 81920;
constexpr int PK_S_HI   = 98304;
constexpr int PK_S_LO   = 102400;
constexpr int PK_E1T_HI = 106496;
constexpr int PK_E1T_LO = 110592;
constexpr int PK_E1B_HI = 114688;
constexpr int PK_E1B_LO = 118784;

typedef short bf16x8 __attribute__((ext_vector_type(8)));
typedef float f32x4  __attribute__((ext_vector_type(4)));

__device__ __forceinline__ short f2bf(float x) {
    unsigned u = __float_as_uint(x);
    u = (u + 0x7fffu + ((u >> 16) & 1u)) >> 16;   // RNE
    return (short)u;
}
__device__ __forceinline__ float bf2f(short h) {
    return __uint_as_float(((unsigned)(unsigned short)h) << 16);
}
__device__ __forceinline__ void splt(float x, short& hi, short& lo) {
    hi = f2bf(x);
    lo = f2bf(x - bf2f(hi));
}

// hi/lo split product: C += Ah*Bh + Ah*Bl + Al*Bh  (error ~2^-17 rel)
__device__ __forceinline__ f32x4 mfma3(bf16x8 ah, bf16x8 al, bf16x8 bh, bf16x8 bl, f32x4 c) {
    c = __builtin_amdgcn_mfma_f32_16x16x32_bf16(ah, bh, c, 0, 0, 0);
    c = __builtin_amdgcn_mfma_f32_16x16x32_bf16(ah, bl, c, 0, 0, 0);
    c = __builtin_amdgcn_mfma_f32_16x16x32_bf16(al, bh, c, 0, 0, 0);
    return c;
}

// A/B fragment from LDS row-major [.][72] bf16: lane holds row=base+(l&15),
// k = kb + (l>>4)*8 + e
__device__ __forceinline__ bf16x8 ldsfrag(const short* p, int rowb, int kb, int lane) {
    return *(const bf16x8*)&p[(rowb + (lane & 15)) * 72 + kb + ((lane >> 4) << 3)];
}
// B fragment from global pack [N][64] bf16
__device__ __forceinline__ bf16x8 gpfrag(const short* p, int colb, int kb, int lane) {
    return *(const bf16x8*)&p[((colb + (lane & 15)) << 6) + kb + ((lane >> 4) << 3)];
}

// unpack 8 consecutive (hi<<16|lo) u32 -> two bf16x8 fragments
__device__ __forceinline__ void unpack8(const unsigned* p, bf16x8& hv, bf16x8& lv) {
    uint4 a = *(const uint4*)p;
    uint4 b = *(const uint4*)(p + 4);
    unsigned u[8] = {a.x, a.y, a.z, a.w, b.x, b.y, b.z, b.w};
    bf16x8 h, l;
    #pragma unroll
    for (int i = 0; i < 8; i++) { h[i] = (short)(u[i] >> 16); l[i] = (short)(u[i] & 0xffffu); }
    hv = h; lv = l;
}

// ---------------------------------------------------------------------------
// Kernel A (merged): blocks 0..239 pack layer-2 weights transposed bf16 hi/lo;
// block 240 computes time embedding + layer-1 class tables.
// ---------------------------------------------------------------------------
__global__ __launch_bounds__(256) void k_tabprep(
    const int* __restrict__ t_ptr,
    const float* __restrict__ Wt,  const float* __restrict__ bt,
    const float* __restrict__ Wq1, const float* __restrict__ bq1,
    const float* __restrict__ Wk1, const float* __restrict__ bk1,
    const float* __restrict__ Wv1, const float* __restrict__ bv1,
    const float* __restrict__ Ws1, const float* __restrict__ bs1,
    const float* __restrict__ Wq2, const float* __restrict__ Wk2,
    const float* __restrict__ Wv2, const float* __restrict__ Ws2,
    const float* __restrict__ We1,
    float* __restrict__ ws, short* __restrict__ wsh)
{
    const int t = threadIdx.x;
    if (blockIdx.x < 240) {   // ---- weight pack path ----
        int b = blockIdx.x;
        const float* src; int N; int dhi; int nb;
        if (b < 64)       { src = Wq2;           N = 256; dhi = PK_Q_HI;   nb = b; }
        else if (b < 128) { src = Wk2;           N = 256; dhi = PK_K_HI;   nb = b - 64; }
        else if (b < 192) { src = Wv2;           N = 256; dhi = PK_V_HI;   nb = b - 128; }
        else if (b < 208) { src = Ws2;           N = 64;  dhi = PK_S_HI;   nb = b - 192; }
        else if (b < 224) { src = We1;           N = 64;  dhi = PK_E1T_HI; nb = b - 208; }
        else              { src = We1 + 64 * 64; N = 64;  dhi = PK_E1B_HI; nb = b - 224; }
        int dlo = dhi + N * 64;
        int n = nb * 4 + (t >> 6), kk = t & 63;
        float v = src[(size_t)kk * N + n];
        short hi, lo; splt(v, hi, lo);
        wsh[dhi + n * 64 + kk] = hi;
        wsh[dlo + n * 64 + kk] = lo;
        return;
    }
    // ---- tables path ----
    __shared__ float se[16], temb[16];
    __shared__ float q1t[4][256], k1t[4][256], v1t[4][256], s1t[4][64];
    if (t < 8) {
        float tv = (float)(*t_ptr) * 0.01f;
        float scale = logf(10000.0f) / 7.0f;
        float e = tv * expf(-(float)t * scale);
        se[t]     = sinf(e);
        se[t + 8] = cosf(e);
    }
    __syncthreads();
    if (t < 16) {
        float acc = bt[t];
        for (int i = 0; i < 16; i++) acc += se[i] * Wt[i * 16 + t];
        temb[t] = acc;
    }
    __syncthreads();
    {
        const int o = t;
        float tq = 0.f, tk = 0.f, tv = 0.f;
        for (int d = 0; d < 16; d++) {
            float td = temb[d];
            tq += td * Wq1[(4 + d) * 256 + o];
            tk += td * Wk1[(4 + d) * 256 + o];
            tv += td * Wv1[(4 + d) * 256 + o];
        }
        for (int c = 0; c < 4; c++) {
            q1t[c][o] = Wq1[c * 256 + o] + tq + bq1[o];
            k1t[c][o] = Wk1[c * 256 + o] + tk + bk1[o];
            v1t[c][o] = Wv1[c * 256 + o] + tv + bv1[o];
        }
        if (o < 64) {
            float ts = 0.f;
            for (int d = 0; d < 16; d++) ts += temb[d] * Ws1[(4 + d) * 64 + o];
            for (int c = 0; c < 4; c++) s1t[c][o] = Ws1[c * 64 + o] + ts + bs1[o];
        }
    }
    __syncthreads();
    for (int idx = t; idx < 1024; idx += 256) {
        int c = idx >> 8, o = idx & 255;
        ws[TAB_Q + idx] = q1t[c][o];
        ws[TAB_K + idx] = k1t[c][o];
        ws[TAB_V + idx] = v1t[c][o];
    }
    ws[TAB_S + t] = s1t[t >> 6][t & 63];
    if (t < 64) {
        int cd = t >> 4, cs = (t >> 2) & 3, h = t & 3;
        float acc = 0.f;
        for (int d = 0; d < 64; d++) acc += q1t[cd][h * 64 + d] * k1t[cs][h * 64 + d];
        ws[TAB_LG + t] = acc * 0.125f;
    }
}

// ---------------------------------------------------------------------------
// k_main: grid 512 = (graph, query-row-half). 512 threads, 8 waves.
// Computes h1 + K/V full (redundant across halves) and Q/S/softmax/PV/skip
// for its 32 query rows -> h2 (f32) to ws. LDS 77 KB -> 2 blocks/CU.
// ---------------------------------------------------------------------------
__global__ __launch_bounds__(512, 4) void k_main(
    const float* __restrict__ x, const int* __restrict__ ei,
    const float* __restrict__ ws, const short* __restrict__ wsh,
    const float* __restrict__ bq, const float* __restrict__ bk,
    const float* __restrict__ bv, const float* __restrict__ bsk,
    float* __restrict__ h2out)
{
    __shared__ __align__(16) char smem[78976];
    short* hHi  = (short*)(smem);            // [64][72]
    short* hLo  = (short*)(smem + 9216);
    short* kHi  = (short*)(smem + 18432);    // [64][72] per-head K
    short* kLo  = (short*)(smem + 27648);
    short* vtHi = (short*)(smem + 36864);    // [64][72] per-head V^T (dim-major)
    short* vtLo = (short*)(smem + 46080);
    short* qHi  = (short*)(smem + 55296);    // [32][72] local-half Q
    short* qLo  = (short*)(smem + 59904);
    float* SPf  = (float*)(smem + 64512);    // [32][68] S f32, then packed P u32
    unsigned* SPu = (unsigned*)(smem + 64512);
    int*   Cc   = (int*)(smem + 73216);      // [32][64] ushort-packed (1024 ints)
    int*   cnt4 = (int*)(smem + 77312);      // [64][4]
    int*   cls  = (int*)(smem + 78336);      // 64
    float* lgs  = (float*)(smem + 78592);    // 64
    float* invs = (float*)(smem + 78848);    // 32
    // P0-P3 scratch aliased over the K region (dead until head-0 K-proj):
    float* v1t    = (float*)(smem + 18432);  // 1024
    float* s1t    = (float*)(smem + 22528);  // 256
    float* alphaF = (float*)(smem + 23552);  // [64][16]

    const int g   = blockIdx.x >> 1;
    const int r0  = (blockIdx.x & 1) * 32;   // query-row half
    const int t   = threadIdx.x;
    const int lane = t & 63, w = t >> 6;
    const int rowbF = (w & 3) * 16;          // K/V full mapping: 2 tiles/wave
    const int chF   = w >> 2;
    const int rbQ   = (w & 1) * 16;          // Q/S/PV/skip: 1 tile/wave (local rows)
    const int cqQ   = (w >> 1) * 16;
    const int lg4   = ((lane >> 4) << 2);
    const int l15   = lane & 15;
    const int row8  = t >> 3;                // 0..63 (h1)
    const int d08   = (t & 7) * 8;

    // ---- P0: tables + zero counters ----------------------------------------
    for (int i = t; i < 1024; i += 512) v1t[i] = ws[TAB_V + i];
    if (t < 256) s1t[t] = ws[TAB_S + t];
    if (t < 64)  lgs[t] = ws[TAB_LG + t];
    if (t < 64) {
        const float* xr = x + (size_t)(g * 64 + t) * 4;
        int c = 0;
        if (xr[1] > 0.5f) c = 1;
        if (xr[2] > 0.5f) c = 2;
        if (xr[3] > 0.5f) c = 3;
        cls[t] = c;
    }
    if (t < 256) cnt4[t] = 0;
    for (int i = t; i < 1024; i += 512) Cc[i] = 0;
    __syncthreads();

    // ---- P1: edge counts ----------------------------------------------------
    {
        int ge = g * EPG + t;
        int ls = ei[ge] - g * 64;
        int ld = ei[ETOT + ge] - g * 64;
        atomicAdd(&cnt4[ld * 4 + cls[ls]], 1);
        int lr = ld - r0;
        if ((unsigned)lr < 32u) {
            int idx = lr * 64 + ls;
            atomicAdd(&Cc[idx >> 1], 1 << ((idx & 1) * 16));
        }
    }
    __syncthreads();

    // ---- P2: layer-1 softmax over <=4 distinct logits (all 64 nodes) -------
    if (t < 256) {
        int n = t >> 2, h = t & 3;
        int cd = cls[n];
        int   c[4]; float l[4];
        #pragma unroll
        for (int cc = 0; cc < 4; cc++) {
            c[cc] = cnt4[n * 4 + cc];
            l[cc] = lgs[cd * 16 + cc * 4 + h];
        }
        float m = -1e30f;
        #pragma unroll
        for (int cc = 0; cc < 4; cc++) if (c[cc] > 0) m = fmaxf(m, l[cc]);
        float e[4]; float den = 0.f;
        #pragma unroll
        for (int cc = 0; cc < 4; cc++) {
            e[cc] = (c[cc] > 0) ? (float)c[cc] * expf(l[cc] - m) : 0.f;
            den += e[cc];
        }
        float inv = (den > 0.f) ? 0.25f / den : 0.f;
        #pragma unroll
        for (int cc = 0; cc < 4; cc++) alphaF[n * 16 + h * 4 + cc] = e[cc] * inv;
    }
    __syncthreads();

    // ---- P3: h1 (full graph) -> bf16 hi/lo ---------------------------------
    {
        int cd = cls[row8];
        float a[16];
        #pragma unroll
        for (int q = 0; q < 16; q++) a[q] = alphaF[row8 * 16 + q];
        #pragma unroll
        for (int jj = 0; jj < 8; jj++) {
            int d = d08 + jj;
            float acc = s1t[cd * 64 + d];
            #pragma unroll
            for (int h = 0; h < 4; h++)
                #pragma unroll
                for (int c = 0; c < 4; c++)
                    acc += a[h * 4 + c] * v1t[c * 256 + h * 64 + d];
            float o = fmaxf(acc, 0.f);
            short hi, lo; splt(o, hi, lo);
            hHi[row8 * 72 + d] = hi;
            hLo[row8 * 72 + d] = lo;
        }
    }
    __syncthreads();

    // ---- P4: A-fragments + skip projection ---------------------------------
    bf16x8 AhF0 = ldsfrag(hHi, rowbF, 0, lane),     AhF1 = ldsfrag(hHi, rowbF, 32, lane);
    bf16x8 AlF0 = ldsfrag(hLo, rowbF, 0, lane),     AlF1 = ldsfrag(hLo, rowbF, 32, lane);
    bf16x8 AhQ0 = ldsfrag(hHi, r0 + rbQ, 0, lane),  AhQ1 = ldsfrag(hHi, r0 + rbQ, 32, lane);
    bf16x8 AlQ0 = ldsfrag(hLo, r0 + rbQ, 0, lane),  AlQ1 = ldsfrag(hLo, r0 + rbQ, 32, lane);

    f32x4 skacc;
    {
        f32x4 a = {0.f, 0.f, 0.f, 0.f};
        a = mfma3(AhQ0, AlQ0, gpfrag(wsh + PK_S_HI, cqQ, 0, lane),
                               gpfrag(wsh + PK_S_LO, cqQ, 0, lane), a);
        a = mfma3(AhQ1, AlQ1, gpfrag(wsh + PK_S_HI, cqQ, 32, lane),
                               gpfrag(wsh + PK_S_LO, cqQ, 32, lane), a);
        float bb = bsk[cqQ + l15];
        #pragma unroll
        for (int r = 0; r < 4; r++) a[r] += bb;
        skacc = a;
    }

    // ---- P5: 4 heads --------------------------------------------------------
    float hacc[4] = {0.f, 0.f, 0.f, 0.f};
    #pragma unroll 1
    for (int h = 0; h < 4; h++) {
        // K (full) + V (full, transposed) : 2 tiles per wave
        #pragma unroll
        for (int ct = 0; ct < 2; ct++) {
            int colb = chF * 32 + ct * 16;
            int gcol = h * 64 + colb;
            f32x4 ka = {0.f, 0.f, 0.f, 0.f}, va = {0.f, 0.f, 0.f, 0.f};
            ka = mfma3(AhF0, AlF0, gpfrag(wsh + PK_K_HI, gcol, 0, lane),
                                    gpfrag(wsh + PK_K_LO, gcol, 0, lane), ka);
            ka = mfma3(AhF1, AlF1, gpfrag(wsh + PK_K_HI, gcol, 32, lane),
                                    gpfrag(wsh + PK_K_LO, gcol, 32, lane), ka);
            va = mfma3(AhF0, AlF0, gpfrag(wsh + PK_V_HI, gcol, 0, lane),
                                    gpfrag(wsh + PK_V_LO, gcol, 0, lane), va);
            va = mfma3(AhF1, AlF1, gpfrag(wsh + PK_V_HI, gcol, 32, lane),
                                    gpfrag(wsh + PK_V_LO, gcol, 32, lane), va);
            float bkv = bk[gcol + l15];
            float bvv = bv[gcol + l15];
            int cc = colb + l15;
            #pragma unroll
            for (int r = 0; r < 4; r++) {
                int rr = rowbF + lg4 + r;
                short hi, lo;
                splt(ka[r] + bkv, hi, lo);
                kHi[rr * 72 + cc] = hi;  kLo[rr * 72 + cc] = lo;
                splt(va[r] + bvv, hi, lo);
                vtHi[cc * 72 + rr] = hi; vtLo[cc * 72 + rr] = lo;
            }
        }
        // Q (our 32 rows): 1 tile per wave, pre-scaled by 1/8
        {
            int gcol = h * 64 + cqQ;
            f32x4 qa = {0.f, 0.f, 0.f, 0.f};
            qa = mfma3(AhQ0, AlQ0, gpfrag(wsh + PK_Q_HI, gcol, 0, lane),
                                    gpfrag(wsh + PK_Q_LO, gcol, 0, lane), qa);
            qa = mfma3(AhQ1, AlQ1, gpfrag(wsh + PK_Q_HI, gcol, 32, lane),
                                    gpfrag(wsh + PK_Q_LO, gcol, 32, lane), qa);
            float bqv = bq[gcol + l15];
            int cc = cqQ + l15;
            #pragma unroll
            for (int r = 0; r < 4; r++) {
                int rr = rbQ + lg4 + r;
                short hi, lo;
                splt((qa[r] + bqv) * 0.125f, hi, lo);
                qHi[rr * 72 + cc] = hi;  qLo[rr * 72 + cc] = lo;
            }
        }
        __syncthreads();   // B1: Q/K/V visible

        // S = Q K^T : 1 tile per wave -> SPf f32
        {
            bf16x8 qh0 = ldsfrag(qHi, rbQ, 0, lane),  qh1 = ldsfrag(qHi, rbQ, 32, lane);
            bf16x8 ql0 = ldsfrag(qLo, rbQ, 0, lane),  ql1 = ldsfrag(qLo, rbQ, 32, lane);
            f32x4 s = {0.f, 0.f, 0.f, 0.f};
            s = mfma3(qh0, ql0, ldsfrag(kHi, cqQ, 0, lane),
                                 ldsfrag(kLo, cqQ, 0, lane), s);
            s = mfma3(qh1, ql1, ldsfrag(kHi, cqQ, 32, lane),
                                 ldsfrag(kLo, cqQ, 32, lane), s);
            int cc = cqQ + l15;
            #pragma unroll
            for (int r = 0; r < 4; r++)
                SPf[(rbQ + lg4 + r) * 68 + cc] = s[r];
        }
        __syncthreads();   // B2: S visible

        // softmax (rows 0..31): in-place f32 -> packed (hi<<16|lo) u32
        if (t < 256) {
            int row = t >> 3, c8 = (t & 7) * 8;
            float4 s0 = *(float4*)&SPf[row * 68 + c8];
            float4 s1 = *(float4*)&SPf[row * 68 + c8 + 4];
            float sv[8] = {s0.x, s0.y, s0.z, s0.w, s1.x, s1.y, s1.z, s1.w};
            int cv[8];
            #pragma unroll
            for (int jj = 0; jj < 8; jj++) {
                int idx = row * 64 + c8 + jj;
                cv[jj] = (Cc[idx >> 1] >> ((idx & 1) * 16)) & 0xffff;
            }
            float m = -1e30f;
            #pragma unroll
            for (int jj = 0; jj < 8; jj++) if (cv[jj] > 0) m = fmaxf(m, sv[jj]);
            m = fmaxf(m, __shfl_xor(m, 1, 8));
            m = fmaxf(m, __shfl_xor(m, 2, 8));
            m = fmaxf(m, __shfl_xor(m, 4, 8));
            float den = 0.f; float p[8];
            #pragma unroll
            for (int jj = 0; jj < 8; jj++) {
                p[jj] = (cv[jj] > 0) ? (float)cv[jj] * expf(sv[jj] - m) : 0.f;
                den += p[jj];
            }
            den += __shfl_xor(den, 1, 8);
            den += __shfl_xor(den, 2, 8);
            den += __shfl_xor(den, 4, 8);
            #pragma unroll
            for (int jj = 0; jj < 8; jj++) {
                short hi, lo; splt(p[jj], hi, lo);
                SPu[row * 68 + c8 + jj] =
                    ((unsigned)(unsigned short)hi << 16) | (unsigned short)lo;
            }
            if ((t & 7) == 0) invs[row] = (den > 0.f) ? 1.f / den : 0.f;
        }
        __syncthreads();   // B3: P packed visible

        // PV: 1 tile per wave
        {
            bf16x8 ph0, pl0, ph1, pl1;
            const unsigned* pp = SPu + (rbQ + l15) * 68 + ((lane >> 4) << 3);
            unpack8(pp, ph0, pl0);
            unpack8(pp + 32, ph1, pl1);
            f32x4 pv = {0.f, 0.f, 0.f, 0.f};
            pv = mfma3(ph0, pl0, ldsfrag(vtHi, cqQ, 0, lane),
                                  ldsfrag(vtLo, cqQ, 0, lane), pv);
            pv = mfma3(ph1, pl1, ldsfrag(vtHi, cqQ, 32, lane),
                                  ldsfrag(vtLo, cqQ, 32, lane), pv);
            #pragma unroll
            for (int r = 0; r < 4; r++)
                hacc[r] += pv[r] * invs[rbQ + lg4 + r];
        }
        __syncthreads();   // B4: protect next head's overwrites
    }

    // ---- P6: h2 = relu(mean_heads + skip) -> ws (f32) ----------------------
    {
        int cc = cqQ + l15;
        #pragma unroll
        for (int r = 0; r < 4; r++) {
            int lr = rbQ + lg4 + r;
            float v = fmaxf(0.25f * hacc[r] + skacc[r], 0.f);
            h2out[(size_t)(g * 64 + r0 + lr) * 64 + cc] = v;
        }
    }
}

// ---------------------------------------------------------------------------
// k_edge: grid 512 = (graph, row-half). 512 threads. Reads h2 f32 from ws:
// node logits + A = h2@We1top + be1 (our 32 rows), B^T = (h2@We1bot)^T (full),
// then fp32 edge MLP for our 32 rows of the 64x64 pair grid.
// ---------------------------------------------------------------------------
__global__ __launch_bounds__(512, 4) void k_edge(
    const short* __restrict__ wsh, const float* __restrict__ h2g,
    const float* __restrict__ Wn, const float* __restrict__ bn,
    const float* __restrict__ be1, const float* __restrict__ We2,
    const float* __restrict__ be2, float* __restrict__ out)
{
    __shared__ __align__(16) char smem[46080];
    short* h2Hi = (short*)(smem);            // [64][72]
    short* h2Lo = (short*)(smem + 9216);
    float* Af   = (float*)(smem + 18432);    // [32][68]
    float* BTf  = (float*)(smem + 27136);    // [64][68]
    float* WnS  = (float*)(smem + 44544);    // 256
    float* w2s  = (float*)(smem + 45568);    // 128

    const int g  = blockIdx.x >> 1;
    const int r0 = (blockIdx.x & 1) * 32;
    const int t  = threadIdx.x;
    const int lane = t & 63, w = t >> 6;
    const int rowbF = (w & 3) * 16, chF = w >> 2;
    const int rbQ = (w & 1) * 16,   cqQ = (w >> 1) * 16;
    const int lg4 = ((lane >> 4) << 2);
    const int l15 = lane & 15;

    // load h2 (full graph) -> bf16 hi/lo
    {
        int row = t >> 3, c8 = (t & 7) * 8;
        float4 a = *(const float4*)&h2g[(size_t)(g * 64 + row) * 64 + c8];
        float4 b = *(const float4*)&h2g[(size_t)(g * 64 + row) * 64 + c8 + 4];
        float vv[8] = {a.x, a.y, a.z, a.w, b.x, b.y, b.z, b.w};
        #pragma unroll
        for (int i = 0; i < 8; i++) {
            short hi, lo; splt(vv[i], hi, lo);
            h2Hi[row * 72 + c8 + i] = hi;
            h2Lo[row * 72 + c8 + i] = lo;
        }
    }
    if (t < 256) WnS[t] = Wn[t];
    if (t < 128) w2s[(t & 1) * 64 + (t >> 1)] = We2[t];
    __syncthreads();

    // A (our rows, 1 tile/wave) and B^T (full, 2 tiles/wave)
    {
        bf16x8 aq0 = ldsfrag(h2Hi, r0 + rbQ, 0, lane), aq1 = ldsfrag(h2Hi, r0 + rbQ, 32, lane);
        bf16x8 lq0 = ldsfrag(h2Lo, r0 + rbQ, 0, lane), lq1 = ldsfrag(h2Lo, r0 + rbQ, 32, lane);
        f32x4 aa = {0.f, 0.f, 0.f, 0.f};
        aa = mfma3(aq0, lq0, gpfrag(wsh + PK_E1T_HI, cqQ, 0, lane),
                              gpfrag(wsh + PK_E1T_LO, cqQ, 0, lane), aa);
        aa = mfma3(aq1, lq1, gpfrag(wsh + PK_E1T_HI, cqQ, 32, lane),
                              gpfrag(wsh + PK_E1T_LO, cqQ, 32, lane), aa);
        float bev = be1[cqQ + l15];
        #pragma unroll
        for (int r = 0; r < 4; r++)
            Af[(rbQ + lg4 + r) * 68 + cqQ + l15] = aa[r] + bev;

        bf16x8 af0 = ldsfrag(h2Hi, rowbF, 0, lane), af1 = ldsfrag(h2Hi, rowbF, 32, lane);
        bf16x8 lf0 = ldsfrag(h2Lo, rowbF, 0, lane), lf1 = ldsfrag(h2Lo, rowbF, 32, lane);
        #pragma unroll
        for (int ct = 0; ct < 2; ct++) {
            int colb = chF * 32 + ct * 16;
            f32x4 bb = {0.f, 0.f, 0.f, 0.f};
            bb = mfma3(af0, lf0, gpfrag(wsh + PK_E1B_HI, colb, 0, lane),
                                  gpfrag(wsh + PK_E1B_LO, colb, 0, lane), bb);
            bb = mfma3(af1, lf1, gpfrag(wsh + PK_E1B_HI, colb, 32, lane),
                                  gpfrag(wsh + PK_E1B_LO, colb, 32, lane), bb);
            int cc = colb + l15;
            #pragma unroll
            for (int r = 0; r < 4; r++)
                BTf[cc * 68 + rowbF + lg4 + r] = bb[r];
        }
    }
    // node logits for our 32 rows
    if (t < 128) {
        int n = t >> 2, c = t & 3;
        float acc = bn[c];
        #pragma unroll 4
        for (int k = 0; k < 64; k++)
            acc += (bf2f(h2Hi[(r0 + n) * 72 + k]) + bf2f(h2Lo[(r0 + n) * 72 + k])) * WnS[k * 4 + c];
        out[(size_t)(g * 64 + r0 + n) * 4 + c] = acc;
    }
    __syncthreads();

    // edge MLP: wave wv handles 4 rows, lane j
    {
        const int wv = t >> 6, j = t & 63;
        float e0[4], e1[4];
        const float cb0 = be2[0], cb1 = be2[1];
        #pragma unroll
        for (int ii = 0; ii < 4; ii++) { e0[ii] = cb0; e1[ii] = cb1; }
        for (int kb = 0; kb < 4; kb++) {
            const int k0 = kb * 16;
            float bj[16], wa[16], wb[16];
            #pragma unroll
            for (int q = 0; q < 16; q++) {
                bj[q] = BTf[(k0 + q) * 68 + j];
                wa[q] = w2s[k0 + q];
                wb[q] = w2s[64 + k0 + q];
            }
            #pragma unroll
            for (int ii = 0; ii < 4; ii++) {
                const float* ar = &Af[(wv * 4 + ii) * 68 + k0];
                #pragma unroll
                for (int q = 0; q < 16; q += 4) {
                    float4 a4 = *(const float4*)(ar + q);
                    float s;
                    s = fmaxf(a4.x + bj[q + 0], 0.f); e0[ii] += s * wa[q + 0]; e1[ii] += s * wb[q + 0];
                    s = fmaxf(a4.y + bj[q + 1], 0.f); e0[ii] += s * wa[q + 1]; e1[ii] += s * wb[q + 1];
                    s = fmaxf(a4.z + bj[q + 2], 0.f); e0[ii] += s * wa[q + 2]; e1[ii] += s * wb[q + 2];
                    s = fmaxf(a4.w + bj[q + 3], 0.f); e0[ii] += s * wa[q + 3]; e1[ii] += s * wb[q + 3];
                }
            }
        }
        float2* oe = (float2*)(out + 65536);
        #pragma unroll
        for (int ii = 0; ii < 4; ii++)
            oe[(size_t)(g * 64 + r0 + wv * 4 + ii) * 64 + j] = make_float2(e0[ii], e1[ii]);
    }
}

// ---------------------------------------------------------------------------
extern "C" void kernel_launch(void* const* d_in, const int* in_sizes, int n_in,
                              void* d_out, int out_size, void* d_ws, size_t ws_size,
                              hipStream_t stream)
{
    const float* x    = (const float*)d_in[0];
    const int*   ei   = (const int*)d_in[1];
    const int*   tptr = (const int*)d_in[3];
    const float* Wt   = (const float*)d_in[4];
    const float* bt   = (const float*)d_in[5];
    const float* Wq1  = (const float*)d_in[6];
    const float* bq1  = (const float*)d_in[7];
    const float* Wk1  = (const float*)d_in[8];
    const float* bk1  = (const float*)d_in[9];
    const float* Wv1  = (const float*)d_in[10];
    const float* bv1  = (const float*)d_in[11];
    const float* Ws1  = (const float*)d_in[12];
    const float* bs1  = (const float*)d_in[13];
    const float* Wq2  = (const float*)d_in[14];
    const float* bq2  = (const float*)d_in[15];
    const float* Wk2  = (const float*)d_in[16];
    const float* bk2  = (const float*)d_in[17];
    const float* Wv2  = (const float*)d_in[18];
    const float* bv2  = (const float*)d_in[19];
    const float* Ws2  = (const float*)d_in[20];
    const float* bs2  = (const float*)d_in[21];
    const float* Wn   = (const float*)d_in[22];
    const float* bn   = (const float*)d_in[23];
    const float* We1  = (const float*)d_in[24];
    const float* be1  = (const float*)d_in[25];
    const float* We2  = (const float*)d_in[26];
    const float* be2  = (const float*)d_in[27];

    float* ws  = (float*)d_ws;
    short* wsh = (short*)(ws + 4096);
    float* h2  = ws + OFF_H2;
    float* out = (float*)d_out;

    k_tabprep<<<241, 256, 0, stream>>>(tptr, Wt, bt, Wq1, bq1, Wk1, bk1, Wv1, bv1,
                                       Ws1, bs1, Wq2, Wk2, Wv2, Ws2, We1, ws, wsh);
    k_main<<<512, 512, 0, stream>>>(x, ei, ws, wsh, bq2, bk2, bv2, bs2, h2);
    k_edge<<<512, 512, 0, stream>>>(wsh, h2, Wn, bn, be1, We2, be2, out);
}

// Round 5
// 65.820 us; speedup vs baseline: 1.1591x; 1.1591x over previous
//
#include <hip/hip_runtime.h>
#include <math.h>

// Problem constants
constexpr int EPG  = 512;     // edges per graph
constexpr int ETOT = 131072;  // total edges

// ws float-region offsets (floats)
constexpr size_t TAB_Q  = 0;
constexpr size_t TAB_K  = 1024;
constexpr size_t TAB_V  = 2048;
constexpr size_t TAB_S  = 3072;   // 4*64
constexpr size_t TAB_LG = 3328;   // 64
constexpr size_t TAB_VV = 3392;   // 4*64 scaled v-vectors (col-term)
constexpr size_t OFF_H2P = 65536; // packed h2 u32 [16384][64]

// ws short-region offsets (shorts), region starts at (short*)(ws + 4096)
constexpr int PK_V_HI   = 0;      // Wv2^T [256][64]
constexpr int PK_V_LO   = 16384;
constexpr int PK_S_HI   = 32768;  // Ws2^T [64][64]
constexpr int PK_S_LO   = 36864;
constexpr int PK_E1T_HI = 40960;
constexpr int PK_E1T_LO = 45056;
constexpr int PK_E1B_HI = 49152;
constexpr int PK_E1B_LO = 53248;
constexpr int PK_M_HI   = 57344;  // per head +4096: pack[m][k] = M~[k][m]
constexpr int PK_M_LO   = 73728;

typedef short bf16x8 __attribute__((ext_vector_type(8)));
typedef float f32x4  __attribute__((ext_vector_type(4)));

__device__ __forceinline__ short f2bf(float x) {
    unsigned u = __float_as_uint(x);
    u = (u + 0x7fffu + ((u >> 16) & 1u)) >> 16;   // RNE
    return (short)u;
}
__device__ __forceinline__ float bf2f(short h) {
    return __uint_as_float(((unsigned)(unsigned short)h) << 16);
}
__device__ __forceinline__ void splt(float x, short& hi, short& lo) {
    hi = f2bf(x);
    lo = f2bf(x - bf2f(hi));
}

// hi/lo split product: C += Ah*Bh + Ah*Bl + Al*Bh  (error ~2^-17 rel)
__device__ __forceinline__ f32x4 mfma3(bf16x8 ah, bf16x8 al, bf16x8 bh, bf16x8 bl, f32x4 c) {
    c = __builtin_amdgcn_mfma_f32_16x16x32_bf16(ah, bh, c, 0, 0, 0);
    c = __builtin_amdgcn_mfma_f32_16x16x32_bf16(ah, bl, c, 0, 0, 0);
    c = __builtin_amdgcn_mfma_f32_16x16x32_bf16(al, bh, c, 0, 0, 0);
    return c;
}

// A/B fragment from LDS row-major [.][72] bf16: lane holds row=base+(l&15),
// k = kb + (l>>4)*8 + e
__device__ __forceinline__ bf16x8 ldsfrag(const short* p, int rowb, int kb, int lane) {
    return *(const bf16x8*)&p[(rowb + (lane & 15)) * 72 + kb + ((lane >> 4) << 3)];
}
// A/B fragment from global pack [N][64] bf16
__device__ __forceinline__ bf16x8 gpfrag(const short* p, int colb, int kb, int lane) {
    return *(const bf16x8*)&p[((colb + (lane & 15)) << 6) + kb + ((lane >> 4) << 3)];
}

// unpack 8 consecutive (hi<<16|lo) u32 -> two bf16x8 fragments
__device__ __forceinline__ void unpack8(const unsigned* p, bf16x8& hv, bf16x8& lv) {
    uint4 a = *(const uint4*)p;
    uint4 b = *(const uint4*)(p + 4);
    unsigned u[8] = {a.x, a.y, a.z, a.w, b.x, b.y, b.z, b.w};
    bf16x8 h, l;
    #pragma unroll
    for (int i = 0; i < 8; i++) { h[i] = (short)(u[i] >> 16); l[i] = (short)(u[i] & 0xffffu); }
    hv = h; lv = l;
}

// ---------------------------------------------------------------------------
// k_tabprep: b<112 weight packs; b in [112,116) per-head M~ = Wq Wk^T /8 and
// v~ = Wk bq /8; b==116 time embedding + layer-1 class tables.
// ---------------------------------------------------------------------------
__global__ __launch_bounds__(256) void k_tabprep(
    const int* __restrict__ t_ptr,
    const float* __restrict__ Wt,  const float* __restrict__ bt,
    const float* __restrict__ Wq1, const float* __restrict__ bq1,
    const float* __restrict__ Wk1, const float* __restrict__ bk1,
    const float* __restrict__ Wv1, const float* __restrict__ bv1,
    const float* __restrict__ Ws1, const float* __restrict__ bs1,
    const float* __restrict__ Wq2, const float* __restrict__ bq2,
    const float* __restrict__ Wk2, const float* __restrict__ Wv2,
    const float* __restrict__ Ws2, const float* __restrict__ We1,
    float* __restrict__ ws, short* __restrict__ wsh)
{
    const int t = threadIdx.x, b = blockIdx.x;
    if (b < 112) {   // ---- weight pack path (transposed, bf16 hi/lo) ----
        const float* src; int N; int dhi; int nb;
        if (b < 64)      { src = Wv2;           N = 256; dhi = PK_V_HI;   nb = b; }
        else if (b < 80) { src = Ws2;           N = 64;  dhi = PK_S_HI;   nb = b - 64; }
        else if (b < 96) { src = We1;           N = 64;  dhi = PK_E1T_HI; nb = b - 80; }
        else             { src = We1 + 64 * 64; N = 64;  dhi = PK_E1B_HI; nb = b - 96; }
        int dlo = dhi + N * 64;
        int n = nb * 4 + (t >> 6), kk = t & 63;
        float v = src[(size_t)kk * N + n];
        short hi, lo; splt(v, hi, lo);
        wsh[dhi + n * 64 + kk] = hi;
        wsh[dlo + n * 64 + kk] = lo;
        return;
    }
    if (b < 116) {   // ---- M~ head block ----
        int h = b - 112;
        __shared__ float wq[64][65], wk[64][65];
        for (int i = t; i < 4096; i += 256) {
            int r = i >> 6, a = i & 63;
            wq[r][a] = Wq2[(size_t)r * 256 + h * 64 + a];
            wk[r][a] = Wk2[(size_t)r * 256 + h * 64 + a];
        }
        __syncthreads();
        int m = t >> 2, k0 = (t & 3) * 16;
        for (int kk = k0; kk < k0 + 16; kk++) {
            float acc = 0.f;
            for (int a = 0; a < 64; a++) acc += wq[kk][a] * wk[m][a];
            acc *= 0.125f;
            short hi, lo; splt(acc, hi, lo);
            wsh[PK_M_HI + h * 4096 + m * 64 + kk] = hi;
            wsh[PK_M_LO + h * 4096 + m * 64 + kk] = lo;
        }
        if (t < 64) {
            float acc = 0.f;
            for (int a = 0; a < 64; a++) acc += wk[t][a] * bq2[h * 64 + a];
            ws[TAB_VV + h * 64 + t] = 0.125f * acc;
        }
        return;
    }
    // ---- tables path ----
    __shared__ float se[16], temb[16];
    __shared__ float q1t[4][256], k1t[4][256], v1t[4][256], s1t[4][64];
    if (t < 8) {
        float tv = (float)(*t_ptr) * 0.01f;
        float scale = logf(10000.0f) / 7.0f;
        float e = tv * expf(-(float)t * scale);
        se[t]     = sinf(e);
        se[t + 8] = cosf(e);
    }
    __syncthreads();
    if (t < 16) {
        float acc = bt[t];
        for (int i = 0; i < 16; i++) acc += se[i] * Wt[i * 16 + t];
        temb[t] = acc;
    }
    __syncthreads();
    {
        const int o = t;
        float tq = 0.f, tk = 0.f, tv = 0.f;
        for (int d = 0; d < 16; d++) {
            float td = temb[d];
            tq += td * Wq1[(4 + d) * 256 + o];
            tk += td * Wk1[(4 + d) * 256 + o];
            tv += td * Wv1[(4 + d) * 256 + o];
        }
        for (int c = 0; c < 4; c++) {
            q1t[c][o] = Wq1[c * 256 + o] + tq + bq1[o];
            k1t[c][o] = Wk1[c * 256 + o] + tk + bk1[o];
            v1t[c][o] = Wv1[c * 256 + o] + tv + bv1[o];
        }
        if (o < 64) {
            float ts = 0.f;
            for (int d = 0; d < 16; d++) ts += temb[d] * Ws1[(4 + d) * 64 + o];
            for (int c = 0; c < 4; c++) s1t[c][o] = Ws1[c * 64 + o] + ts + bs1[o];
        }
    }
    __syncthreads();
    for (int idx = t; idx < 1024; idx += 256) {
        int c = idx >> 8, o = idx & 255;
        ws[TAB_Q + idx] = q1t[c][o];
        ws[TAB_K + idx] = k1t[c][o];
        ws[TAB_V + idx] = v1t[c][o];
    }
    ws[TAB_S + t] = s1t[t >> 6][t & 63];
    if (t < 64) {
        int cd = t >> 4, cs = (t >> 2) & 3, h = t & 3;
        float acc = 0.f;
        for (int d = 0; d < 64; d++) acc += q1t[cd][h * 64 + d] * k1t[cs][h * 64 + d];
        ws[TAB_LG + t] = acc * 0.125f;
    }
}

// ---------------------------------------------------------------------------
// k_main: grid 512 = (graph, query-row-half). 512 threads, 8 waves.
// Lean attention: G = h1 M~^T ; S = G h1^T ; in-wave softmax (+col term) ;
// V^T = Wv-pack x h1 (direct transpose via operand swap) ; PV.
// 3 barriers/head. h2 written packed (hi|lo) u32.
// ---------------------------------------------------------------------------
__global__ __launch_bounds__(512, 4) void k_main(
    const float* __restrict__ x, const int* __restrict__ ei,
    const float* __restrict__ ws, const short* __restrict__ wsh,
    const float* __restrict__ bv, const float* __restrict__ bsk,
    unsigned* __restrict__ h2p)
{
    __shared__ __align__(16) char smem[61184];
    short* hHi  = (short*)(smem);            // [64][72]
    short* hLo  = (short*)(smem + 9216);
    short* GHi  = (short*)(smem + 18432);    // [32][72]
    short* GLo  = (short*)(smem + 23040);
    short* VtHi = (short*)(smem + 27648);    // [64][72] (d-major)
    short* VtLo = (short*)(smem + 36864);
    float* SPf  = (float*)(smem + 46080);    // [32][68] S f32
    int*   Cc   = (int*)(smem + 54784);      // [32][66] ushort-packed (1056 ints)
    float* wcol = (float*)(smem + 59136);    // [4][64]
    float* vvs  = (float*)(smem + 60160);    // 256
    // P0-P3 scratch aliased over Vt region (dead until head-0 phase A):
    float* v1t    = (float*)(smem + 27648);  // 1024
    float* s1t    = (float*)(smem + 31744);  // 256
    float* lgs    = (float*)(smem + 32768);  // 64
    float* alphaF = (float*)(smem + 33024);  // 1024
    int*   cls    = (int*)(smem + 37120);    // 64
    int*   cnt4   = (int*)(smem + 37376);    // 256

    const int g   = blockIdx.x >> 1;
    const int r0  = (blockIdx.x & 1) * 32;   // query-row half
    const int t   = threadIdx.x;
    const int lane = t & 63, w = t >> 6;
    const int rb  = (w & 1) * 16;            // local row band (G/S/PV/skip)
    const int cb  = (w >> 1) * 16;           // col band (m / j / d)
    const int db  = (w & 3) * 16;            // Vt: d band
    const int jb0 = (w >> 2) * 32;           // Vt: j bands jb0, jb0+16
    const int lg4 = ((lane >> 4) << 2);
    const int lg8 = ((lane >> 4) << 3);
    const int l15 = lane & 15;
    const int row8 = t >> 3;                 // 0..63 (h1 phase)
    const int d08  = (t & 7) * 8;

    // ---- P0: tables + zero counters ----------------------------------------
    for (int i = t; i < 1024; i += 512) v1t[i] = ws[TAB_V + i];
    if (t < 256) s1t[t] = ws[TAB_S + t];
    if (t < 64)  lgs[t] = ws[TAB_LG + t];
    if (t < 256) vvs[t] = ws[TAB_VV + t];
    if (t < 64) {
        const float* xr = x + (size_t)(g * 64 + t) * 4;
        int c = 0;
        if (xr[1] > 0.5f) c = 1;
        if (xr[2] > 0.5f) c = 2;
        if (xr[3] > 0.5f) c = 3;
        cls[t] = c;
    }
    if (t < 256) cnt4[t] = 0;
    for (int i = t; i < 1056; i += 512) Cc[i] = 0;
    __syncthreads();

    // ---- P1: edge counts ----------------------------------------------------
    {
        int ge = g * EPG + t;
        int ls = ei[ge] - g * 64;
        int ld = ei[ETOT + ge] - g * 64;
        atomicAdd(&cnt4[ld * 4 + cls[ls]], 1);
        int lr = ld - r0;
        if ((unsigned)lr < 32u) {
            int idx = lr * 66 + ls;
            atomicAdd(&Cc[idx >> 1], 1 << ((idx & 1) * 16));
        }
    }
    __syncthreads();

    // ---- P2: layer-1 softmax over <=4 distinct logits -----------------------
    if (t < 256) {
        int n = t >> 2, h = t & 3;
        int cd = cls[n];
        int   c[4]; float l[4];
        #pragma unroll
        for (int cc = 0; cc < 4; cc++) {
            c[cc] = cnt4[n * 4 + cc];
            l[cc] = lgs[cd * 16 + cc * 4 + h];
        }
        float m = -1e30f;
        #pragma unroll
        for (int cc = 0; cc < 4; cc++) if (c[cc] > 0) m = fmaxf(m, l[cc]);
        float e[4]; float den = 0.f;
        #pragma unroll
        for (int cc = 0; cc < 4; cc++) {
            e[cc] = (c[cc] > 0) ? (float)c[cc] * __expf(l[cc] - m) : 0.f;
            den += e[cc];
        }
        float inv = (den > 0.f) ? 0.25f / den : 0.f;
        #pragma unroll
        for (int cc = 0; cc < 4; cc++) alphaF[n * 16 + h * 4 + cc] = e[cc] * inv;
    }
    __syncthreads();

    // ---- P3: h1 (full graph) -> bf16 hi/lo ---------------------------------
    {
        int cd = cls[row8];
        float a[16];
        #pragma unroll
        for (int q = 0; q < 16; q++) a[q] = alphaF[row8 * 16 + q];
        #pragma unroll
        for (int jj = 0; jj < 8; jj++) {
            int d = d08 + jj;
            float acc = s1t[cd * 64 + d];
            #pragma unroll
            for (int h = 0; h < 4; h++)
                #pragma unroll
                for (int c = 0; c < 4; c++)
                    acc += a[h * 4 + c] * v1t[c * 256 + h * 64 + d];
            float o = fmaxf(acc, 0.f);
            short hi, lo; splt(o, hi, lo);
            hHi[row8 * 72 + d] = hi;
            hLo[row8 * 72 + d] = lo;
        }
    }
    __syncthreads();

    // ---- cached fragments (constant across heads) --------------------------
    bf16x8 AhQ0 = ldsfrag(hHi, r0 + rb, 0, lane),  AhQ1 = ldsfrag(hHi, r0 + rb, 32, lane);
    bf16x8 AlQ0 = ldsfrag(hLo, r0 + rb, 0, lane),  AlQ1 = ldsfrag(hLo, r0 + rb, 32, lane);
    bf16x8 sb0h = ldsfrag(hHi, cb, 0, lane),  sb0l = ldsfrag(hLo, cb, 0, lane);
    bf16x8 sb1h = ldsfrag(hHi, cb, 32, lane), sb1l = ldsfrag(hLo, cb, 32, lane);

    // ---- w-col term: wcol[h][j] = h1_j . v~_h --------------------------------
    if (t < 256) {
        int j = t >> 2, hh = t & 3;
        float acc = 0.f;
        #pragma unroll 8
        for (int k = 0; k < 64; k++)
            acc += (bf2f(hHi[j * 72 + k]) + bf2f(hLo[j * 72 + k])) * vvs[hh * 64 + k];
        wcol[hh * 64 + j] = acc;
    }

    // ---- skip projection (grouped loads) ------------------------------------
    f32x4 skacc = {0.f, 0.f, 0.f, 0.f};
    {
        bf16x8 s0h = gpfrag(wsh + PK_S_HI, cb, 0, lane),  s0l = gpfrag(wsh + PK_S_LO, cb, 0, lane);
        bf16x8 s1h = gpfrag(wsh + PK_S_HI, cb, 32, lane), s1l = gpfrag(wsh + PK_S_LO, cb, 32, lane);
        skacc = mfma3(AhQ0, AlQ0, s0h, s0l, skacc);
        skacc = mfma3(AhQ1, AlQ1, s1h, s1l, skacc);
        float bb = bsk[cb + l15];
        #pragma unroll
        for (int r = 0; r < 4; r++) skacc[r] += bb;
    }

    // ---- head loop: 3 barriers per head -------------------------------------
    float hacc[4] = {0.f, 0.f, 0.f, 0.f};
    #pragma unroll 1
    for (int h = 0; h < 4; h++) {
        // --- phase A: grouped global loads, then G & V^T ---
        const short* pmh = wsh + PK_M_HI + h * 4096;
        const short* pml = wsh + PK_M_LO + h * 4096;
        bf16x8 m0h = gpfrag(pmh, cb, 0, lane),  m0l = gpfrag(pml, cb, 0, lane);
        bf16x8 m1h = gpfrag(pmh, cb, 32, lane), m1l = gpfrag(pml, cb, 32, lane);
        int gc0 = h * 64 + db;
        bf16x8 va0h = gpfrag(wsh + PK_V_HI, gc0, 0, lane),  va0l = gpfrag(wsh + PK_V_LO, gc0, 0, lane);
        bf16x8 va1h = gpfrag(wsh + PK_V_HI, gc0, 32, lane), va1l = gpfrag(wsh + PK_V_LO, gc0, 32, lane);
        float4 bv4 = *(const float4*)&bv[gc0 + lg4];
        // h1 B-frags for the two Vt tiles
        bf16x8 hb00 = ldsfrag(hHi, jb0, 0, lane),       hb00l = ldsfrag(hLo, jb0, 0, lane);
        bf16x8 hb01 = ldsfrag(hHi, jb0, 32, lane),      hb01l = ldsfrag(hLo, jb0, 32, lane);
        bf16x8 hb10 = ldsfrag(hHi, jb0 + 16, 0, lane),  hb10l = ldsfrag(hLo, jb0 + 16, 0, lane);
        bf16x8 hb11 = ldsfrag(hHi, jb0 + 16, 32, lane), hb11l = ldsfrag(hLo, jb0 + 16, 32, lane);

        {   // G tile (local rows rb, cols m = cb)
            f32x4 ga = {0.f, 0.f, 0.f, 0.f};
            ga = mfma3(AhQ0, AlQ0, m0h, m0l, ga);
            ga = mfma3(AhQ1, AlQ1, m1h, m1l, ga);
            int cc = cb + l15;
            #pragma unroll
            for (int r = 0; r < 4; r++) {
                short hi, lo; splt(ga[r], hi, lo);
                GHi[(rb + lg4 + r) * 72 + cc] = hi;
                GLo[(rb + lg4 + r) * 72 + cc] = lo;
            }
        }
        {   // V^T tiles (rows d = db, cols j = jb0 / jb0+16)
            f32x4 vt0 = {0.f, 0.f, 0.f, 0.f}, vt1 = {0.f, 0.f, 0.f, 0.f};
            vt0 = mfma3(va0h, va0l, hb00, hb00l, vt0);
            vt0 = mfma3(va1h, va1l, hb01, hb01l, vt0);
            vt1 = mfma3(va0h, va0l, hb10, hb10l, vt1);
            vt1 = mfma3(va1h, va1l, hb11, hb11l, vt1);
            #pragma unroll
            for (int r = 0; r < 4; r++) {
                int rr = (db + lg4 + r) * 72;
                short hi, lo;
                splt(vt0[r] + bv4[r], hi, lo);
                VtHi[rr + jb0 + l15] = hi;      VtLo[rr + jb0 + l15] = lo;
                splt(vt1[r] + bv4[r], hi, lo);
                VtHi[rr + jb0 + 16 + l15] = hi; VtLo[rr + jb0 + 16 + l15] = lo;
            }
        }
        __syncthreads();   // B1: G, V^T visible

        // --- phase B: S = G h1^T (+ early V^T B-frag reads for phase C) ---
        bf16x8 vb0h = ldsfrag(VtHi, cb, 0, lane),  vb0l = ldsfrag(VtLo, cb, 0, lane);
        bf16x8 vb1h = ldsfrag(VtHi, cb, 32, lane), vb1l = ldsfrag(VtLo, cb, 32, lane);
        {
            bf16x8 g0h = ldsfrag(GHi, rb, 0, lane),  g0l = ldsfrag(GLo, rb, 0, lane);
            bf16x8 g1h = ldsfrag(GHi, rb, 32, lane), g1l = ldsfrag(GLo, rb, 32, lane);
            f32x4 s = {0.f, 0.f, 0.f, 0.f};
            s = mfma3(g0h, g0l, sb0h, sb0l, s);
            s = mfma3(g1h, g1l, sb1h, sb1l, s);
            int cc = cb + l15;
            #pragma unroll
            for (int r = 0; r < 4; r++)
                SPf[(rb + lg4 + r) * 68 + cc] = s[r];
        }
        __syncthreads();   // B2: S visible

        // --- phase C: in-wave softmax -> P~ frags -> PV ---
        {
            const int lr = rb + l15;               // local row this lane owns
            float sv[16];
            {
                float4 a0 = *(const float4*)&SPf[lr * 68 + lg8];
                float4 a1 = *(const float4*)&SPf[lr * 68 + lg8 + 4];
                float4 a2 = *(const float4*)&SPf[lr * 68 + 32 + lg8];
                float4 a3 = *(const float4*)&SPf[lr * 68 + 32 + lg8 + 4];
                sv[0]=a0.x; sv[1]=a0.y; sv[2]=a0.z; sv[3]=a0.w;
                sv[4]=a1.x; sv[5]=a1.y; sv[6]=a1.z; sv[7]=a1.w;
                sv[8]=a2.x; sv[9]=a2.y; sv[10]=a2.z; sv[11]=a2.w;
                sv[12]=a3.x; sv[13]=a3.y; sv[14]=a3.z; sv[15]=a3.w;
            }
            int cv[16];
            #pragma unroll
            for (int e = 0; e < 8; e++) {
                int i0 = lr * 66 + lg8 + e;
                int i1 = lr * 66 + 32 + lg8 + e;
                cv[e]     = (Cc[i0 >> 1] >> ((i0 & 1) * 16)) & 0xffff;
                cv[8 + e] = (Cc[i1 >> 1] >> ((i1 & 1) * 16)) & 0xffff;
                sv[e]     += wcol[h * 64 + lg8 + e];
                sv[8 + e] += wcol[h * 64 + 32 + lg8 + e];
            }
            float m = -1e30f;
            #pragma unroll
            for (int e = 0; e < 16; e++) if (cv[e] > 0) m = fmaxf(m, sv[e]);
            m = fmaxf(m, __shfl_xor(m, 16));
            m = fmaxf(m, __shfl_xor(m, 32));
            float den = 0.f; float p[16];
            #pragma unroll
            for (int e = 0; e < 16; e++) {
                p[e] = (cv[e] > 0) ? (float)cv[e] * __expf(sv[e] - m) : 0.f;
                den += p[e];
            }
            den += __shfl_xor(den, 16);
            den += __shfl_xor(den, 32);
            float inv = (den > 0.f) ? 1.f / den : 0.f;
            bf16x8 pa0h, pa0l, pa1h, pa1l;
            #pragma unroll
            for (int e = 0; e < 8; e++) {
                short hi, lo;
                splt(p[e] * inv, hi, lo);      pa0h[e] = hi; pa0l[e] = lo;
                splt(p[8 + e] * inv, hi, lo);  pa1h[e] = hi; pa1l[e] = lo;
            }
            f32x4 pv = {0.f, 0.f, 0.f, 0.f};
            pv = mfma3(pa0h, pa0l, vb0h, vb0l, pv);
            pv = mfma3(pa1h, pa1l, vb1h, vb1l, pv);
            #pragma unroll
            for (int r = 0; r < 4; r++) hacc[r] += pv[r];
        }
        __syncthreads();   // B3: protect G/V^T/S for next head
    }

    // ---- h2 = relu(mean_heads + skip) -> packed u32 global -----------------
    {
        int cc = cb + l15;
        #pragma unroll
        for (int r = 0; r < 4; r++) {
            float v = fmaxf(0.25f * hacc[r] + skacc[r], 0.f);
            short hi, lo; splt(v, hi, lo);
            unsigned u = ((unsigned)(unsigned short)hi << 16) | (unsigned short)(unsigned short)lo;
            h2p[(size_t)(g * 64 + r0 + rb + lg4 + r) * 64 + cc] = u;
        }
    }
}

// ---------------------------------------------------------------------------
// k_edge: grid 512 = (graph, row-half). Reads packed h2. Node logits +
// A = h2@We1top + be1 (our 32 rows), B^T = (h2@We1bot)^T (full), fp32 edge MLP.
// ---------------------------------------------------------------------------
__global__ __launch_bounds__(512, 4) void k_edge(
    const short* __restrict__ wsh, const unsigned* __restrict__ h2g,
    const float* __restrict__ Wn, const float* __restrict__ bn,
    const float* __restrict__ be1, const float* __restrict__ We2,
    const float* __restrict__ be2, float* __restrict__ out)
{
    __shared__ __align__(16) char smem[45056];
    unsigned* h2P = (unsigned*)(smem);       // [64][68] packed
    float* Af   = (float*)(smem + 17408);    // [32][68]
    float* BTf  = (float*)(smem + 26112);    // [64][68]
    float* WnS  = (float*)(smem + 43520);    // 256
    float* w2s  = (float*)(smem + 44544);    // 128

    const int g  = blockIdx.x >> 1;
    const int r0 = (blockIdx.x & 1) * 32;
    const int t  = threadIdx.x;
    const int lane = t & 63, w = t >> 6;
    const int rowbF = (w & 3) * 16, chF = w >> 2;
    const int rbQ = (w & 1) * 16,   cqQ = (w >> 1) * 16;
    const int lg4 = ((lane >> 4) << 2);
    const int lg8 = ((lane >> 4) << 3);
    const int l15 = lane & 15;

    {   // load packed h2 (full graph)
        int row = t >> 3, c8 = (t & 7) * 8;
        uint4 a = *(const uint4*)&h2g[(size_t)(g * 64 + row) * 64 + c8];
        uint4 b = *(const uint4*)&h2g[(size_t)(g * 64 + row) * 64 + c8 + 4];
        *(uint4*)&h2P[row * 68 + c8]     = a;
        *(uint4*)&h2P[row * 68 + c8 + 4] = b;
    }
    if (t < 256) WnS[t] = Wn[t];
    if (t < 128) w2s[(t & 1) * 64 + (t >> 1)] = We2[t];
    __syncthreads();

    {   // A (our rows, 1 tile/wave) with grouped loads
        bf16x8 e0h = gpfrag(wsh + PK_E1T_HI, cqQ, 0, lane),  e0l = gpfrag(wsh + PK_E1T_LO, cqQ, 0, lane);
        bf16x8 e1h = gpfrag(wsh + PK_E1T_HI, cqQ, 32, lane), e1l = gpfrag(wsh + PK_E1T_LO, cqQ, 32, lane);
        bf16x8 aq0, lq0, aq1, lq1;
        unpack8(&h2P[(r0 + rbQ + l15) * 68 + lg8], aq0, lq0);
        unpack8(&h2P[(r0 + rbQ + l15) * 68 + 32 + lg8], aq1, lq1);
        f32x4 aa = {0.f, 0.f, 0.f, 0.f};
        aa = mfma3(aq0, lq0, e0h, e0l, aa);
        aa = mfma3(aq1, lq1, e1h, e1l, aa);
        float bev = be1[cqQ + l15];
        #pragma unroll
        for (int r = 0; r < 4; r++)
            Af[(rbQ + lg4 + r) * 68 + cqQ + l15] = aa[r] + bev;
    }
    {   // B^T (full graph, 2 tiles/wave)
        bf16x8 af0, lf0, af1, lf1;
        unpack8(&h2P[(rowbF + l15) * 68 + lg8], af0, lf0);
        unpack8(&h2P[(rowbF + l15) * 68 + 32 + lg8], af1, lf1);
        #pragma unroll
        for (int ct = 0; ct < 2; ct++) {
            int colb = chF * 32 + ct * 16;
            bf16x8 b0h = gpfrag(wsh + PK_E1B_HI, colb, 0, lane),  b0l = gpfrag(wsh + PK_E1B_LO, colb, 0, lane);
            bf16x8 b1h = gpfrag(wsh + PK_E1B_HI, colb, 32, lane), b1l = gpfrag(wsh + PK_E1B_LO, colb, 32, lane);
            f32x4 bb = {0.f, 0.f, 0.f, 0.f};
            bb = mfma3(af0, lf0, b0h, b0l, bb);
            bb = mfma3(af1, lf1, b1h, b1l, bb);
            int cc = colb + l15;
            #pragma unroll
            for (int r = 0; r < 4; r++)
                BTf[cc * 68 + rowbF + lg4 + r] = bb[r];
        }
    }
    // node logits for our 32 rows
    if (t < 128) {
        int n = t >> 2, c = t & 3;
        float acc = bn[c];
        #pragma unroll 8
        for (int k = 0; k < 64; k++) {
            unsigned u = h2P[(r0 + n) * 68 + k];
            float val = __uint_as_float(u & 0xffff0000u) + __uint_as_float(u << 16);
            acc += val * WnS[k * 4 + c];
        }
        out[(size_t)(g * 64 + r0 + n) * 4 + c] = acc;
    }
    __syncthreads();

    // edge MLP: wave wv handles 4 rows, lane j
    {
        const int wv = t >> 6, j = t & 63;
        float e0[4], e1[4];
        const float cb0 = be2[0], cb1 = be2[1];
        #pragma unroll
        for (int ii = 0; ii < 4; ii++) { e0[ii] = cb0; e1[ii] = cb1; }
        for (int kb = 0; kb < 4; kb++) {
            const int k0 = kb * 16;
            float bj[16], wa[16], wb[16];
            #pragma unroll
            for (int q = 0; q < 16; q++) {
                bj[q] = BTf[(k0 + q) * 68 + j];
                wa[q] = w2s[k0 + q];
                wb[q] = w2s[64 + k0 + q];
            }
            #pragma unroll
            for (int ii = 0; ii < 4; ii++) {
                const float* ar = &Af[(wv * 4 + ii) * 68 + k0];
                #pragma unroll
                for (int q = 0; q < 16; q += 4) {
                    float4 a4 = *(const float4*)(ar + q);
                    float s;
                    s = fmaxf(a4.x + bj[q + 0], 0.f); e0[ii] += s * wa[q + 0]; e1[ii] += s * wb[q + 0];
                    s = fmaxf(a4.y + bj[q + 1], 0.f); e0[ii] += s * wa[q + 1]; e1[ii] += s * wb[q + 1];
                    s = fmaxf(a4.z + bj[q + 2], 0.f); e0[ii] += s * wa[q + 2]; e1[ii] += s * wb[q + 2];
                    s = fmaxf(a4.w + bj[q + 3], 0.f); e0[ii] += s * wa[q + 3]; e1[ii] += s * wb[q + 3];
                }
            }
        }
        float2* oe = (float2*)(out + 65536);
        #pragma unroll
        for (int ii = 0; ii < 4; ii++)
            oe[(size_t)(g * 64 + r0 + wv * 4 + ii) * 64 + j] = make_float2(e0[ii], e1[ii]);
    }
}

// ---------------------------------------------------------------------------
extern "C" void kernel_launch(void* const* d_in, const int* in_sizes, int n_in,
                              void* d_out, int out_size, void* d_ws, size_t ws_size,
                              hipStream_t stream)
{
    const float* x    = (const float*)d_in[0];
    const int*   ei   = (const int*)d_in[1];
    const int*   tptr = (const int*)d_in[3];
    const float* Wt   = (const float*)d_in[4];
    const float* bt   = (const float*)d_in[5];
    const float* Wq1  = (const float*)d_in[6];
    const float* bq1  = (const float*)d_in[7];
    const float* Wk1  = (const float*)d_in[8];
    const float* bk1  = (const float*)d_in[9];
    const float* Wv1  = (const float*)d_in[10];
    const float* bv1  = (const float*)d_in[11];
    const float* Ws1  = (const float*)d_in[12];
    const float* bs1  = (const float*)d_in[13];
    const float* Wq2  = (const float*)d_in[14];
    const float* bq2  = (const float*)d_in[15];
    const float* Wk2  = (const float*)d_in[16];
    const float* Wv2  = (const float*)d_in[18];
    const float* bv2  = (const float*)d_in[19];
    const float* Ws2  = (const float*)d_in[20];
    const float* bs2  = (const float*)d_in[21];
    const float* Wn   = (const float*)d_in[22];
    const float* bn   = (const float*)d_in[23];
    const float* We1  = (const float*)d_in[24];
    const float* be1  = (const float*)d_in[25];
    const float* We2  = (const float*)d_in[26];
    const float* be2  = (const float*)d_in[27];

    float* ws  = (float*)d_ws;
    short* wsh = (short*)(ws + 4096);
    unsigned* h2p = (unsigned*)(ws + OFF_H2P);
    float* out = (float*)d_out;

    k_tabprep<<<117, 256, 0, stream>>>(tptr, Wt, bt, Wq1, bq1, Wk1, bk1, Wv1, bv1,
                                       Ws1, bs1, Wq2, bq2, Wk2, Wv2, Ws2, We1, ws, wsh);
    k_main<<<512, 512, 0, stream>>>(x, ei, ws, wsh, bv2, bs2, h2p);
    k_edge<<<512, 512, 0, stream>>>(wsh, h2p, Wn, bn, be1, We2, be2, out);
}